// Round 6
// baseline (194.162 us; speedup 1.0000x reference)
//
#include <hip/hip_runtime.h>
#include <stdint.h>

// VanillaRNN fused: B=2048,S=125,I=2,H=300,O=2
// h_t = relu(x_t@W_ih^T + b_ih + h_{t-1}@W_hh^T + b_hh) + 0.01*noise_t
// out = h_t @ W_out^T + b_out
//
// 256 WGs x 640 threads (10 waves); each WG owns 8 batch rows for all 125
// steps. Each wave owns 32 hidden columns as even/odd pairs (c0=n0+2lc,
// c1=c0+1); wf = 2x10 frags = 80 VGPR. R5 post-mortem: __launch_bounds__'s
// 2nd arg is only an occupancy FLOOR -- LLVM's memory-bound perf-hint bumped
// desired occupancy to 6 waves/EU (VGPR_Count=84) and spilled wf to scratch
// (WRITE_SIZE 35MB vs 2.4MB legit). amdgpu_waves_per_eu(3,3) pins min AND
// max -> budget 512/3=170 regs -> wf truly persists in registers.
// W_out rides as pad COLUMNS 300/301 (wave 9, lane 6) -> no output reduce.
// Plain __syncthreads() (raw s_barrier is not a compiler fence; R4 raced).

#define SEQ   125
#define HID   300
#define APAD  328     // Abuf row stride in shorts; 656B rows, 16B-aligned
#define KT    10
#define WAVES 10
#define NTH   (WAVES * 64)
#define RPW   8       // batch rows per WG

typedef __attribute__((ext_vector_type(8))) short bf16x8;
typedef __attribute__((ext_vector_type(4))) float f32x4;

__device__ __forceinline__ short f2bf(float f) {
  union { float f; uint32_t u; } v; v.f = f;
  uint32_t r = (v.u + 0x7fffu + ((v.u >> 16) & 1u)) >> 16;  // RNE
  return (short)r;
}

__device__ __forceinline__ uint32_t cvt_pk_bf16(float lo, float hi) {
  uint32_t r;
  asm("v_cvt_pk_bf16_f32 %0, %1, %2" : "=v"(r) : "v"(lo), "v"(hi));
  return r;
}

__global__ __launch_bounds__(NTH)
__attribute__((amdgpu_waves_per_eu(3, 3)))
void rnn_fused(
    const float* __restrict__ x,      // [2048,125,2]
    const float* __restrict__ noise,  // [2048,125,300]
    const float* __restrict__ W_ih,   // [300,2]
    const float* __restrict__ b_ih,   // [300]
    const float* __restrict__ W_hh,   // [300,300]
    const float* __restrict__ b_hh,   // [300]
    const float* __restrict__ W_out,  // [2,300]
    const float* __restrict__ b_out,  // [2]
    float* __restrict__ out)          // [2048,125,2]
{
  __shared__ __align__(16) short Abuf[2][16][APAD];  // h (bf16), dbuf; rows 8..15 stay 0
  __shared__ float xbuf[RPW][SEQ * 2];               // staged x
  __shared__ float outbuf[RPW][SEQ * 2];             // staged outputs

  const int tid  = threadIdx.x;
  const int wave = tid >> 6;
  const int lane = tid & 63;
  const int grp  = lane >> 4;     // 0..3
  const int lc   = lane & 15;     // 0..15
  const int row0 = blockIdx.x * RPW;
  const int n0   = wave << 5;     // wave's 32-col base
  const int c0   = n0 + 2 * lc;   // even col
  const int c1   = c0 + 1;        // odd col
  const bool v0  = (c0 < HID), v1 = (c1 < HID);
  const bool rowv = (grp < 2);    // rows grp*4+r valid (RPW=8)

  // zero both h buffers (pad cols/rows harmless or stay 0)
  for (int i = tid; i < 2 * 16 * APAD / 2; i += NTH)
    ((uint32_t*)Abuf)[i] = 0u;
  // stage x
  for (int i = tid; i < RPW * SEQ * 2; i += NTH) {
    int r = i / (SEQ * 2), j = i % (SEQ * 2);
    xbuf[r][j] = x[(row0 + r) * (SEQ * 2) + j];
  }

  // per-lane column constants (zeroed for pad cols)
  const float wih00 = v0 ? W_ih[c0 * 2 + 0] : 0.f;
  const float wih10 = v0 ? W_ih[c0 * 2 + 1] : 0.f;
  const float wih01 = v1 ? W_ih[c1 * 2 + 0] : 0.f;
  const float wih11 = v1 ? W_ih[c1 * 2 + 1] : 0.f;
  const float biasc0 = v0 ? (b_ih[c0] + b_hh[c0]) : 0.f;
  const float biasc1 = v1 ? (b_ih[c1] + b_hh[c1]) : 0.f;
  const float nsc = v0 ? 0.01f : 0.f;
  const float bout0 = b_out[0], bout1 = b_out[1];

  // persistent B fragments: lane supplies cols c0 (wf0) / c1 (wf1) at MFMA n=lc.
  // cols 300/301 carry W_out rows 0/1 (fused output projection).
  bf16x8 wf0[KT], wf1[KT];
#pragma unroll
  for (int kt = 0; kt < KT; ++kt) {
    bf16x8 f0, f1;
#pragma unroll
    for (int e = 0; e < 8; ++e) {
      int k = kt * 32 + grp * 8 + e;
      float a = 0.f, b = 0.f;
      if (k < HID) {
        if (c0 < HID)           a = W_hh[c0 * HID + k];
        else if (c0 == HID)     a = W_out[k];
        if (c1 < HID)           b = W_hh[c1 * HID + k];
        else if (c1 == HID)     b = W_out[k];
        else if (c1 == HID + 1) b = W_out[HID + k];
      }
      f0[e] = f2bf(a);
      f1[e] = f2bf(b);
    }
    wf0[kt] = f0; wf1[kt] = f1;
  }

  // noise addressing; clamped col for invalid lanes (loads guarded anyway)
  const int cc0 = v0 ? c0 : 0;
  int noff[4];
#pragma unroll
  for (int r = 0; r < 4; ++r) {
    int b = row0 + (grp & 1) * 4 + r;
    noff[r] = b * (SEQ * HID) + cc0 + HID;  // pre-advanced to s=1
  }

  // preload noise for s=0 (pair of adjacent cols -> float2)
  float2 nbA[4] = {}, nbB[4] = {};
  if (rowv && v0 && v1) {
#pragma unroll
    for (int r = 0; r < 4; ++r)
      nbA[r] = *(const float2*)&noise[noff[r] - HID];
  }

  __syncthreads();

  // Iteration S (0..125): MFMA on h_{S-1}; extract out[S-1] (S>=1);
  // epilogue builds h_S (S<125). 126 iterations total.
#define ITER(S, NBC, NBN)                                                      \
  {                                                                            \
    const int cur = (S) & 1, nxt = cur ^ 1;                                    \
    if (rowv && v0 && v1 && (S) + 1 < SEQ) {                                   \
      _Pragma("unroll")                                                        \
      for (int r = 0; r < 4; ++r)                                              \
        NBN[r] = *(const float2*)&noise[noff[r]];                              \
    }                                                                          \
    const short* Ab = &Abuf[cur][lc][grp * 8];                                 \
    f32x4 a0a = {0.f,0.f,0.f,0.f}, a0b = {0.f,0.f,0.f,0.f};                    \
    f32x4 a1a = {0.f,0.f,0.f,0.f}, a1b = {0.f,0.f,0.f,0.f};                    \
    _Pragma("unroll")                                                          \
    for (int kt = 0; kt < KT; kt += 2) {                                       \
      bf16x8 aa = *(const bf16x8*)(Ab + kt * 32);                              \
      bf16x8 ab = *(const bf16x8*)(Ab + (kt + 1) * 32);                        \
      a0a = __builtin_amdgcn_mfma_f32_16x16x32_bf16(aa, wf0[kt],     a0a, 0,0,0); \
      a1a = __builtin_amdgcn_mfma_f32_16x16x32_bf16(aa, wf1[kt],     a1a, 0,0,0); \
      a0b = __builtin_amdgcn_mfma_f32_16x16x32_bf16(ab, wf0[kt + 1], a0b, 0,0,0); \
      a1b = __builtin_amdgcn_mfma_f32_16x16x32_bf16(ab, wf1[kt + 1], a1b, 0,0,0); \
    }                                                                          \
    f32x4 ac0 = a0a + a0b, ac1 = a1a + a1b;                                    \
    if ((S) >= 1 && wave == 9 && lc == 6 && rowv) {                            \
      _Pragma("unroll")                                                        \
      for (int r = 0; r < 4; ++r) {                                            \
        outbuf[grp * 4 + r][((S) - 1) * 2 + 0] = ac0[r] + bout0;               \
        outbuf[grp * 4 + r][((S) - 1) * 2 + 1] = ac1[r] + bout1;               \
      }                                                                        \
    }                                                                          \
    if ((S) < SEQ) {                                                           \
      if (rowv) {                                                              \
        _Pragma("unroll")                                                      \
        for (int r = 0; r < 4; ++r) {                                          \
          int lrow = grp * 4 + r;                                              \
          float2 xv = *(const float2*)&xbuf[lrow][(S) * 2];                    \
          float h0 = fmaxf(ac0[r] + xv.x*wih00 + xv.y*wih10 + biasc0, 0.f) + nsc * NBC[r].x; \
          float h1 = fmaxf(ac1[r] + xv.x*wih01 + xv.y*wih11 + biasc1, 0.f) + nsc * NBC[r].y; \
          *(uint32_t*)&Abuf[nxt][lrow][c0] = cvt_pk_bf16(h0, h1);              \
        }                                                                      \
      }                                                                        \
      _Pragma("unroll")                                                        \
      for (int r = 0; r < 4; ++r) noff[r] += HID;                              \
      __syncthreads();                                                         \
    }                                                                          \
  }

  for (int sb = 0; sb < SEQ; sb += 2) {  // sb = 0,2,...,124 -> S = 0..125
    ITER(sb, nbA, nbB);
    ITER(sb + 1, nbB, nbA);
  }
#undef ITER

  __syncthreads();  // outbuf visible to all

  // coalesced flush of staged outputs
  for (int i = tid; i < RPW * SEQ * 2; i += NTH) {
    int r = i / (SEQ * 2), j = i % (SEQ * 2);
    out[(row0 + r) * (SEQ * 2) + j] = outbuf[r][j];
  }
}

extern "C" void kernel_launch(void* const* d_in, const int* in_sizes, int n_in,
                              void* d_out, int out_size, void* d_ws, size_t ws_size,
                              hipStream_t stream) {
  const float* xp     = (const float*)d_in[0];
  const float* noise  = (const float*)d_in[1];
  const float* W_ih   = (const float*)d_in[2];
  const float* b_ih   = (const float*)d_in[3];
  const float* W_hh   = (const float*)d_in[4];
  const float* b_hh   = (const float*)d_in[5];
  const float* W_out  = (const float*)d_in[6];
  const float* b_out  = (const float*)d_in[7];
  float* outp         = (float*)d_out;

  rnn_fused<<<dim3(2048 / RPW), dim3(NTH), 0, stream>>>(
      xp, noise, W_ih, b_ih, W_hh, b_hh, W_out, b_out, outp);
}